// Round 1
// baseline (1334.648 us; speedup 1.0000x reference)
//
#include <hip/hip_runtime.h>

#define NR 2000000
#define NC 128

// ws layout: [ e: NR floats ][ sums: 2 doubles ]  (NR*4 = 8,000,000 B, 8-aligned)

__global__ void init_sums_kernel(double* sums) {
    sums[0] = 0.0;
    sums[1] = 0.0;
}

// Block-level sum; result valid only on threadIdx.x == 0. blockDim.x == 256.
__device__ __forceinline__ float block_sum_256(float v) {
    #pragma unroll
    for (int m = 32; m >= 1; m >>= 1) v += __shfl_xor(v, m, 64);
    __shared__ float red[4];
    if ((threadIdx.x & 63) == 0) red[threadIdx.x >> 6] = v;
    __syncthreads();
    float s = 0.0f;
    if (threadIdx.x == 0) s = red[0] + red[1] + red[2] + red[3];
    return s;
}

// Pass 1: per-row cosine sim vs key, e = exp(beta*(1+cos)), accumulate sum(e).
// One 32-lane half-wave per row: lane loads float4 -> 512B coalesced per row.
__global__ __launch_bounds__(256) void pass1_kernel(
    const float* __restrict__ mem, const float* __restrict__ kvec,
    const float* __restrict__ beta_p, float* __restrict__ e_out,
    double* __restrict__ sum_e) {
    const int tid = threadIdx.x;
    const int sub = tid & 31;  // lane within half-wave
    const float beta = *beta_p;

    // Preload kq = k + 1e-16 (4 elems/lane covers all 128 cols per half-wave).
    float4 kq = *reinterpret_cast<const float4*>(kvec + sub * 4);
    kq.x += 1e-16f; kq.y += 1e-16f; kq.z += 1e-16f; kq.w += 1e-16f;
    float kn = kq.x * kq.x + kq.y * kq.y + kq.z * kq.z + kq.w * kq.w;
    #pragma unroll
    for (int m = 16; m >= 1; m >>= 1) kn += __shfl_xor(kn, m, 64);
    const float k_norm = fmaxf(sqrtf(kn), 1e-12f);

    const int hw_in_block = blockDim.x >> 5;  // 8 half-waves per block
    long long row = (long long)blockIdx.x * hw_in_block + (tid >> 5);
    const long long hw_total = (long long)gridDim.x * hw_in_block;

    float local = 0.0f;
    for (; row < NR; row += hw_total) {
        const float4 m4 =
            *reinterpret_cast<const float4*>(mem + row * NC + sub * 4);
        const float ax = m4.x + 1e-16f, ay = m4.y + 1e-16f;
        const float az = m4.z + 1e-16f, aw = m4.w + 1e-16f;
        float dot = ax * kq.x + ay * kq.y + az * kq.z + aw * kq.w;
        float nrm = ax * ax + ay * ay + az * az + aw * aw;
        // Butterfly within the 32-lane half-wave (xor masks < 32 stay closed).
        #pragma unroll
        for (int m = 16; m >= 1; m >>= 1) {
            dot += __shfl_xor(dot, m, 64);
            nrm += __shfl_xor(nrm, m, 64);
        }
        const float row_norm = fmaxf(sqrtf(nrm), 1e-12f);
        const float cosv = dot / (row_norm * k_norm);
        // beta*(1+cos) in [0, ~11] -> exp is fp32-safe, no max subtraction.
        const float ev = expf(beta * (1.0f + cosv));
        if (sub == 0) {
            e_out[row] = ev;
            local += ev;
        }
    }
    const float s = block_sum_256(local);
    if (threadIdx.x == 0) atomicAdd(sum_e, (double)s);
}

// Pass 2: wg = g*wc + (1-g)*w_prev, 3-tap circular shift, sharpen w = wh^gamma.
// Writes w into d_out, accumulates sum(w). e/w_prev are 8MB -> L2/L3 resident,
// so the i-1/i/i+1 overlapping reads are cheap.
__global__ __launch_bounds__(256) void pass2_kernel(
    const float* __restrict__ e, const float* __restrict__ w_prev,
    const float* __restrict__ g_p, const float* __restrict__ s_p,
    const float* __restrict__ gamma_p, const double* __restrict__ sum_e,
    float* __restrict__ w_out, double* __restrict__ sum_w) {
    const float g = *g_p;
    const float omg = 1.0f - g;
    const float s0 = s_p[0], s1 = s_p[1], s2 = s_p[2];
    const float gamma = *gamma_p;
    const float inv_se = (float)(1.0 / *sum_e);

    const int stride = gridDim.x * blockDim.x;
    float local = 0.0f;
    for (int i = blockIdx.x * blockDim.x + threadIdx.x; i < NR; i += stride) {
        const int im1 = (i == 0) ? (NR - 1) : (i - 1);
        const int ip1 = (i == NR - 1) ? 0 : (i + 1);
        const float wm = g * (e[im1] * inv_se) + omg * w_prev[im1];
        const float w0 = g * (e[i] * inv_se) + omg * w_prev[i];
        const float wp = g * (e[ip1] * inv_se) + omg * w_prev[ip1];
        const float wh = s0 * wm + s1 * w0 + s2 * wp;  // all terms > 0
        const float w = powf(wh, gamma);
        w_out[i] = w;
        local += w;
    }
    const float s = block_sum_256(local);
    if (threadIdx.x == 0) atomicAdd(sum_w, (double)s);
}

// Pass 3: in-place normalize out by 1/(sum_w + 1e-16).
__global__ __launch_bounds__(256) void pass3_kernel(
    float* __restrict__ out, const double* __restrict__ sum_w) {
    const float inv = (float)(1.0 / (*sum_w + 1e-16));
    const int stride = gridDim.x * blockDim.x;
    for (int i = blockIdx.x * blockDim.x + threadIdx.x; i < NR; i += stride)
        out[i] *= inv;
}

extern "C" void kernel_launch(void* const* d_in, const int* in_sizes, int n_in,
                              void* d_out, int out_size, void* d_ws,
                              size_t ws_size, hipStream_t stream) {
    const float* mem   = (const float*)d_in[0];
    const float* k     = (const float*)d_in[1];
    const float* beta  = (const float*)d_in[2];
    const float* g     = (const float*)d_in[3];
    const float* s     = (const float*)d_in[4];
    const float* gamma = (const float*)d_in[5];
    const float* wprev = (const float*)d_in[6];
    float* out = (float*)d_out;

    float* e = (float*)d_ws;
    double* sums = (double*)((char*)d_ws + (size_t)NR * sizeof(float));

    init_sums_kernel<<<1, 1, 0, stream>>>(sums);
    // 4096 blocks * 8 rows/block-iter = 32768 half-waves; ~61 rows each.
    pass1_kernel<<<4096, 256, 0, stream>>>(mem, k, beta, e, &sums[0]);
    pass2_kernel<<<2048, 256, 0, stream>>>(e, wprev, g, s, gamma, &sums[0],
                                           out, &sums[1]);
    pass3_kernel<<<2048, 256, 0, stream>>>(out, &sums[1]);
}

// Round 2
// 1321.081 us; speedup vs baseline: 1.0103x; 1.0103x over previous
//
#include <hip/hip_runtime.h>

#define NR 2000000
#define NC 128

// ws layout: [ e: NR floats ][ sums: 2 doubles ]  (NR*4 = 8,000,000 B, 8-aligned)

__global__ void init_sums_kernel(double* sums) {
    sums[0] = 0.0;
    sums[1] = 0.0;
}

// Block-level sum; result valid only on threadIdx.x == 0. blockDim.x == 256.
__device__ __forceinline__ float block_sum_256(float v) {
    #pragma unroll
    for (int m = 32; m >= 1; m >>= 1) v += __shfl_xor(v, m, 64);
    __shared__ float red[4];
    if ((threadIdx.x & 63) == 0) red[threadIdx.x >> 6] = v;
    __syncthreads();
    float s = 0.0f;
    if (threadIdx.x == 0) s = red[0] + red[1] + red[2] + red[3];
    return s;
}

// Pass 1: per-row cosine sim vs key, e = exp(beta*(1+cos)), accumulate sum(e).
// 16 lanes per row, 8 floats (two float4) per lane -> 4 rows / 2 KB per wave
// per iteration; 4 butterfly steps x 2 values = 8 shuffle ops per 2 KB.
__global__ __launch_bounds__(256) void pass1_kernel(
    const float* __restrict__ mem, const float* __restrict__ kvec,
    const float* __restrict__ beta_p, float* __restrict__ e_out,
    double* __restrict__ sum_e) {
    const int tid = threadIdx.x;
    const int sub = tid & 15;  // lane within 16-lane row group
    const float beta = *beta_p;

    // Preload kq = k + 1e-16 (8 elems/lane covers all 128 cols per group).
    float4 kq0 = *reinterpret_cast<const float4*>(kvec + sub * 8);
    float4 kq1 = *reinterpret_cast<const float4*>(kvec + sub * 8 + 4);
    kq0.x += 1e-16f; kq0.y += 1e-16f; kq0.z += 1e-16f; kq0.w += 1e-16f;
    kq1.x += 1e-16f; kq1.y += 1e-16f; kq1.z += 1e-16f; kq1.w += 1e-16f;
    float kn = kq0.x * kq0.x + kq0.y * kq0.y + kq0.z * kq0.z + kq0.w * kq0.w +
               kq1.x * kq1.x + kq1.y * kq1.y + kq1.z * kq1.z + kq1.w * kq1.w;
    #pragma unroll
    for (int m = 8; m >= 1; m >>= 1) kn += __shfl_xor(kn, m, 64);
    const float k_norm = fmaxf(sqrtf(kn), 1e-12f);

    const int rpb = blockDim.x >> 4;  // 16 rows per block per sweep
    long long row = (long long)blockIdx.x * rpb + (tid >> 4);
    const long long row_stride = (long long)gridDim.x * rpb;

    const float* p = mem + row * NC + sub * 8;
    const long long p_stride = row_stride * NC;

    float local = 0.0f;
    for (; row < NR; row += row_stride, p += p_stride) {
        const float4 a0 = *reinterpret_cast<const float4*>(p);
        const float4 a1 = *reinterpret_cast<const float4*>(p + 4);
        const float x0 = a0.x + 1e-16f, x1 = a0.y + 1e-16f;
        const float x2 = a0.z + 1e-16f, x3 = a0.w + 1e-16f;
        const float x4 = a1.x + 1e-16f, x5 = a1.y + 1e-16f;
        const float x6 = a1.z + 1e-16f, x7 = a1.w + 1e-16f;
        float dot = x0 * kq0.x + x1 * kq0.y + x2 * kq0.z + x3 * kq0.w +
                    x4 * kq1.x + x5 * kq1.y + x6 * kq1.z + x7 * kq1.w;
        float nrm = x0 * x0 + x1 * x1 + x2 * x2 + x3 * x3 +
                    x4 * x4 + x5 * x5 + x6 * x6 + x7 * x7;
        // Butterfly within the 16-lane group (xor masks < 16 stay closed).
        #pragma unroll
        for (int m = 8; m >= 1; m >>= 1) {
            dot += __shfl_xor(dot, m, 64);
            nrm += __shfl_xor(nrm, m, 64);
        }
        const float row_norm = fmaxf(sqrtf(nrm), 1e-12f);
        const float cosv = dot / (row_norm * k_norm);
        // beta*(1+cos) in [0, ~11] -> exp is fp32-safe, no max subtraction.
        const float ev = expf(beta * (1.0f + cosv));
        if (sub == 0) {
            e_out[row] = ev;
            local += ev;
        }
    }
    const float s = block_sum_256(local);
    if (threadIdx.x == 0) atomicAdd(sum_e, (double)s);
}

// Pass 2: wg = g*wc + (1-g)*w_prev, 3-tap circular shift, sharpen w = wh^gamma.
// Writes w into d_out, accumulates sum(w). e/w_prev are 8MB -> L2/L3 resident,
// so the i-1/i/i+1 overlapping reads are cheap.
__global__ __launch_bounds__(256) void pass2_kernel(
    const float* __restrict__ e, const float* __restrict__ w_prev,
    const float* __restrict__ g_p, const float* __restrict__ s_p,
    const float* __restrict__ gamma_p, const double* __restrict__ sum_e,
    float* __restrict__ w_out, double* __restrict__ sum_w) {
    const float g = *g_p;
    const float omg = 1.0f - g;
    const float s0 = s_p[0], s1 = s_p[1], s2 = s_p[2];
    const float gamma = *gamma_p;
    const float inv_se = (float)(1.0 / *sum_e);

    const int stride = gridDim.x * blockDim.x;
    float local = 0.0f;
    for (int i = blockIdx.x * blockDim.x + threadIdx.x; i < NR; i += stride) {
        const int im1 = (i == 0) ? (NR - 1) : (i - 1);
        const int ip1 = (i == NR - 1) ? 0 : (i + 1);
        const float wm = g * (e[im1] * inv_se) + omg * w_prev[im1];
        const float w0 = g * (e[i] * inv_se) + omg * w_prev[i];
        const float wp = g * (e[ip1] * inv_se) + omg * w_prev[ip1];
        const float wh = s0 * wm + s1 * w0 + s2 * wp;  // all terms > 0
        const float w = powf(wh, gamma);
        w_out[i] = w;
        local += w;
    }
    const float s = block_sum_256(local);
    if (threadIdx.x == 0) atomicAdd(sum_w, (double)s);
}

// Pass 3: in-place normalize out by 1/(sum_w + 1e-16).
__global__ __launch_bounds__(256) void pass3_kernel(
    float* __restrict__ out, const double* __restrict__ sum_w) {
    const float inv = (float)(1.0 / (*sum_w + 1e-16));
    const int stride = gridDim.x * blockDim.x;
    for (int i = blockIdx.x * blockDim.x + threadIdx.x; i < NR; i += stride)
        out[i] *= inv;
}

extern "C" void kernel_launch(void* const* d_in, const int* in_sizes, int n_in,
                              void* d_out, int out_size, void* d_ws,
                              size_t ws_size, hipStream_t stream) {
    const float* mem   = (const float*)d_in[0];
    const float* k     = (const float*)d_in[1];
    const float* beta  = (const float*)d_in[2];
    const float* g     = (const float*)d_in[3];
    const float* s     = (const float*)d_in[4];
    const float* gamma = (const float*)d_in[5];
    const float* wprev = (const float*)d_in[6];
    float* out = (float*)d_out;

    float* e = (float*)d_ws;
    double* sums = (double*)((char*)d_ws + (size_t)NR * sizeof(float));

    init_sums_kernel<<<1, 1, 0, stream>>>(sums);
    // 4096 blocks * 16 rows/block-sweep = 65536 rows/sweep; ~31 sweeps.
    pass1_kernel<<<4096, 256, 0, stream>>>(mem, k, beta, e, &sums[0]);
    pass2_kernel<<<2048, 256, 0, stream>>>(e, wprev, g, s, gamma, &sums[0],
                                           out, &sums[1]);
    pass3_kernel<<<2048, 256, 0, stream>>>(out, &sums[1]);
}